// Round 1
// baseline (559.872 us; speedup 1.0000x reference)
//
#include <hip/hip_runtime.h>
#include <math.h>

namespace {
constexpr int Bn = 32, Hn = 1024, Wn = 1024;
constexpr int STRIP = 16;                     // rows per block (divides Hn)
constexpr int GRID1 = Bn * Hn / STRIP;        // 2048 blocks -> 8 KB partials
constexpr float BWGT = 3.0f;
}

__device__ inline float4 vmax4(float4 a, float4 b) {
    return make_float4(fmaxf(a.x,b.x), fmaxf(a.y,b.y), fmaxf(a.z,b.z), fmaxf(a.w,b.w));
}
__device__ inline float4 vmin4(float4 a, float4 b) {
    return make_float4(fminf(a.x,b.x), fminf(a.y,b.y), fminf(a.z,b.z), fminf(a.w,b.w));
}

// Rolling 3-row window + software prefetch, ZERO barriers in the main loop.
// The old LDS wave-edge exchange forced a vmcnt(0)-drain barrier that
// phase-locked all 18 loads before any compute (50% duty on both pipes).
// Halo columns for lanes 0/63 are instead re-read directly from global
// (2 exec-masked 4B loads per row -> L1/L2 hits from the neighbor wave's
// lines). Register footprint is STRIP-independent (~50 VGPR), so
// __launch_bounds__(256,8) holds <=64 regs -> 8 waves/SIMD occupancy.
// Image borders use the binary-target identities (0 for max, 1 for min)
// == reduce_window's -inf/+inf init padding, exact.
__global__ __launch_bounds__(256, 8) void bam_bce_rows(
    const float* __restrict__ pred, const float* __restrict__ tgt,
    float* __restrict__ partial)
{
    const int tid  = threadIdx.x;
    const int lane = tid & 63;
    const int x0   = tid << 2;
    const int rowBase = blockIdx.x * STRIP;   // strips never cross images
    const int y0 = rowBase & (Hn - 1);
    const bool vtop = (y0 != 0);              // row y0-1 exists (block-uniform)
    const bool vbot = (y0 != Hn - STRIP);     // row y0+STRIP exists
    const float* tb = tgt  + (size_t)rowBase * Wn;
    const float* pb = pred + (size_t)rowBase * Wn;

    // halo-column loaders: lane 0 reads x0-1 (left neighbor's .w), lane 63
    // reads x0+4 (right neighbor's .x); image-border lanes load nothing.
    const bool isL = (lane == 0)  && (tid != 0);
    const bool isR = (lane == 63) && (tid != 255);
    const bool isEdge = isL || isR;
    const int  nbx = isL ? (x0 - 1) : (x0 + 4);   // only dereferenced if isEdge

    const float4 z4 = make_float4(0.f, 0.f, 0.f, 0.f);

    // rolling window: target rows (rel) i-1, i, i+1 + halo scalars; pred row i
    float4 t_prev = z4, t_cur, t_next;
    float nb_prev = 0.f, nb_cur = 0.f, nb_next = 0.f;
    if (vtop) {
        t_prev = *reinterpret_cast<const float4*>(tb - Wn + x0);
        if (isEdge) nb_prev = *(tb + nbx - Wn);
    }
    t_cur  = *reinterpret_cast<const float4*>(tb + x0);
    t_next = *reinterpret_cast<const float4*>(tb + Wn + x0);
    if (isEdge) {
        nb_cur  = *(tb + nbx);
        nb_next = *(tb + nbx + Wn);
    }
    float4 p_cur = *reinterpret_cast<const float4*>(pb + x0);

    float sum = 0.0f;
    #pragma unroll
    for (int i = 0; i < STRIP; ++i) {
        // ---- prefetch next iteration's operands BEFORE computing row i ----
        float4 t_nn = z4, p_nn = z4;
        float nb_nn = 0.f;
        if (i < STRIP - 1) {
            p_nn = *reinterpret_cast<const float4*>(pb + (size_t)(i + 1) * Wn + x0);
            if ((i + 2 < STRIP) || vbot) {       // target row i+2 exists
                t_nn = *reinterpret_cast<const float4*>(tb + (size_t)(i + 2) * Wn + x0);
                if (isEdge) nb_nn = *(tb + (size_t)(i + 2) * Wn + nbx);
            }
        }

        const bool useTop = (i > 0) || vtop;           // row i-1 valid
        const bool useBot = (i < STRIP - 1) || vbot;   // row i+1 valid

        // vertical (3-row) max/min for own 4 columns + this lane's halo column
        float4 mx = t_cur, mn = t_cur;
        float  em = nb_cur, en = nb_cur;
        if (useTop) {
            mx = vmax4(mx, t_prev); mn = vmin4(mn, t_prev);
            em = fmaxf(em, nb_prev); en = fminf(en, nb_prev);
        }
        if (useBot) {
            mx = vmax4(mx, t_next); mn = vmin4(mn, t_next);
            em = fmaxf(em, nb_next); en = fminf(en, nb_next);
        }

        // horizontal neighbors: in-wave shuffle, patched at wave/image edges
        float Lmx = __shfl_up(mx.w, 1),   Lmn = __shfl_up(mn.w, 1);
        float Rmx = __shfl_down(mx.x, 1), Rmn = __shfl_down(mn.x, 1);
        if (lane == 0)  { Lmx = em; Lmn = en; }
        if (lane == 63) { Rmx = em; Rmn = en; }
        if (tid == 0)   { Lmx = 0.f; Lmn = 1.f; }      // image left border
        if (tid == 255) { Rmx = 0.f; Rmn = 1.f; }      // image right border

        const float4 t = t_cur;
        const float4 p = p_cur;
        {
            const float wmx = fmaxf(fmaxf(Lmx, mx.x), mx.y);
            const float wmn = fminf(fminf(Lmn, mn.x), mn.y);
            const float w = (wmx > wmn) ? BWGT : 1.0f;
            const float x = (t.x != 0.0f) ? p.x : (1.0f - p.x);
            sum = fmaf(w, -__logf(x), sum);
        }
        {
            const float wmx = fmaxf(fmaxf(mx.x, mx.y), mx.z);
            const float wmn = fminf(fminf(mn.x, mn.y), mn.z);
            const float w = (wmx > wmn) ? BWGT : 1.0f;
            const float x = (t.y != 0.0f) ? p.y : (1.0f - p.y);
            sum = fmaf(w, -__logf(x), sum);
        }
        {
            const float wmx = fmaxf(fmaxf(mx.y, mx.z), mx.w);
            const float wmn = fminf(fminf(mn.y, mn.z), mn.w);
            const float w = (wmx > wmn) ? BWGT : 1.0f;
            const float x = (t.z != 0.0f) ? p.z : (1.0f - p.z);
            sum = fmaf(w, -__logf(x), sum);
        }
        {
            const float wmx = fmaxf(fmaxf(mx.z, mx.w), Rmx);
            const float wmn = fminf(fminf(mn.z, mn.w), Rmn);
            const float w = (wmx > wmn) ? BWGT : 1.0f;
            const float x = (t.w != 0.0f) ? p.w : (1.0f - p.w);
            sum = fmaf(w, -__logf(x), sum);
        }

        // ---- rotate the rolling window ----
        t_prev = t_cur;  t_cur = t_next;  t_next = t_nn;
        nb_prev = nb_cur; nb_cur = nb_next; nb_next = nb_nn;
        p_cur = p_nn;
    }

    // wave(64) shuffle reduce -> 4-wave LDS reduce -> one partial per block
    #pragma unroll
    for (int off = 32; off > 0; off >>= 1) sum += __shfl_down(sum, off);
    __shared__ float smem[4];
    if ((tid & 63) == 0) smem[tid >> 6] = sum;
    __syncthreads();
    if (tid == 0) partial[blockIdx.x] = (smem[0] + smem[1]) + (smem[2] + smem[3]);
}

__global__ __launch_bounds__(256) void bam_bce_reduce(
    const float* __restrict__ partial, float* __restrict__ out)
{
    const int tid = threadIdx.x;
    float s = 0.0f;
    for (int i = tid; i < GRID1; i += 256) s += partial[i];
    #pragma unroll
    for (int off = 32; off > 0; off >>= 1) s += __shfl_down(s, off);
    __shared__ float smem[4];
    if ((tid & 63) == 0) smem[tid >> 6] = s;
    __syncthreads();
    if (tid == 0) {
        const float invN = 1.0f / (float)((long long)Bn * Hn * Wn);  // 1/2^25, exact
        out[0] = ((smem[0] + smem[1]) + (smem[2] + smem[3])) * invN;
    }
}

extern "C" void kernel_launch(void* const* d_in, const int* in_sizes, int n_in,
                              void* d_out, int out_size, void* d_ws, size_t ws_size,
                              hipStream_t stream)
{
    const float* pred = (const float*)d_in[0];
    const float* tgt  = (const float*)d_in[1];
    float* partial = (float*)d_ws;            // 2048 floats = 8 KB, fully
                                              // overwritten each call (poison-safe)
    bam_bce_rows<<<GRID1, 256, 0, stream>>>(pred, tgt, partial);
    bam_bce_reduce<<<1, 256, 0, stream>>>(partial, (float*)d_out);
}

// Round 2
// 303.712 us; speedup vs baseline: 1.8434x; 1.8434x over previous
//
#include <hip/hip_runtime.h>
#include <math.h>

namespace {
constexpr int Bn = 32, Hn = 1024, Wn = 1024;
constexpr int STRIP = 16;                     // rows per block (divides Hn)
constexpr int GRID1 = Bn * Hn / STRIP;        // 2048 blocks -> 8 KB partials
constexpr float BWGT = 3.0f;
}

__device__ inline float4 vmax4(float4 a, float4 b) {
    return make_float4(fmaxf(a.x,b.x), fmaxf(a.y,b.y), fmaxf(a.z,b.z), fmaxf(a.w,b.w));
}
__device__ inline float4 vmin4(float4 a, float4 b) {
    return make_float4(fminf(a.x,b.x), fminf(a.y,b.y), fminf(a.z,b.z), fminf(a.w,b.w));
}

// Rolling 3-row window + software prefetch, ZERO barriers in the main loop.
// Halo columns for lanes 0/63 are re-read directly from global (2 exec-masked
// 4B loads per row -> L1/L2 hits on the neighbor wave's lines) instead of the
// old LDS exchange, whose __syncthreads forced a vmcnt(0) drain that
// phase-locked all loads before any compute.
// R1 lesson: __launch_bounds__(256,8) made the compiler budget 256/8=32 VGPRs
// -> massive scratch spills (WRITE_SIZE 697 MB/dispatch). Plain (256) lets the
// ~50 live regs stay in registers; spill-free matters far more than the extra
// occupancy step.
__global__ __launch_bounds__(256) void bam_bce_rows(
    const float* __restrict__ pred, const float* __restrict__ tgt,
    float* __restrict__ partial)
{
    const int tid  = threadIdx.x;
    const int lane = tid & 63;
    const int x0   = tid << 2;
    const int rowBase = blockIdx.x * STRIP;   // strips never cross images
    const int y0 = rowBase & (Hn - 1);
    const bool vtop = (y0 != 0);              // row y0-1 exists (block-uniform)
    const bool vbot = (y0 != Hn - STRIP);     // row y0+STRIP exists
    const float* tb = tgt  + (size_t)rowBase * Wn;
    const float* pb = pred + (size_t)rowBase * Wn;

    // halo-column loaders: lane 0 reads x0-1 (left neighbor's .w), lane 63
    // reads x0+4 (right neighbor's .x); image-border lanes load nothing.
    const bool isL = (lane == 0)  && (tid != 0);
    const bool isR = (lane == 63) && (tid != 255);
    const bool isEdge = isL || isR;
    const int  nbx = isL ? (x0 - 1) : (x0 + 4);   // only dereferenced if isEdge

    const float4 z4 = make_float4(0.f, 0.f, 0.f, 0.f);

    // rolling window: target rows (rel) i-1, i, i+1 + halo scalars; pred row i
    float4 t_prev = z4, t_cur, t_next;
    float nb_prev = 0.f, nb_cur = 0.f, nb_next = 0.f;
    if (vtop) {
        t_prev = *reinterpret_cast<const float4*>(tb - Wn + x0);
        if (isEdge) nb_prev = *(tb + nbx - Wn);
    }
    t_cur  = *reinterpret_cast<const float4*>(tb + x0);
    t_next = *reinterpret_cast<const float4*>(tb + Wn + x0);
    if (isEdge) {
        nb_cur  = *(tb + nbx);
        nb_next = *(tb + nbx + Wn);
    }
    float4 p_cur = *reinterpret_cast<const float4*>(pb + x0);

    float sum = 0.0f;
    #pragma unroll
    for (int i = 0; i < STRIP; ++i) {
        // ---- prefetch next iteration's operands BEFORE computing row i ----
        float4 t_nn = z4, p_nn = z4;
        float nb_nn = 0.f;
        if (i < STRIP - 1) {
            p_nn = *reinterpret_cast<const float4*>(pb + (size_t)(i + 1) * Wn + x0);
            if ((i + 2 < STRIP) || vbot) {       // target row i+2 exists
                t_nn = *reinterpret_cast<const float4*>(tb + (size_t)(i + 2) * Wn + x0);
                if (isEdge) nb_nn = *(tb + (size_t)(i + 2) * Wn + nbx);
            }
        }

        const bool useTop = (i > 0) || vtop;           // row i-1 valid
        const bool useBot = (i < STRIP - 1) || vbot;   // row i+1 valid

        // vertical (3-row) max/min for own 4 columns + this lane's halo column
        float4 mx = t_cur, mn = t_cur;
        float  em = nb_cur, en = nb_cur;
        if (useTop) {
            mx = vmax4(mx, t_prev); mn = vmin4(mn, t_prev);
            em = fmaxf(em, nb_prev); en = fminf(en, nb_prev);
        }
        if (useBot) {
            mx = vmax4(mx, t_next); mn = vmin4(mn, t_next);
            em = fmaxf(em, nb_next); en = fminf(en, nb_next);
        }

        // horizontal neighbors: in-wave shuffle, patched at wave/image edges
        float Lmx = __shfl_up(mx.w, 1),   Lmn = __shfl_up(mn.w, 1);
        float Rmx = __shfl_down(mx.x, 1), Rmn = __shfl_down(mn.x, 1);
        if (lane == 0)  { Lmx = em; Lmn = en; }
        if (lane == 63) { Rmx = em; Rmn = en; }
        if (tid == 0)   { Lmx = 0.f; Lmn = 1.f; }      // image left border
        if (tid == 255) { Rmx = 0.f; Rmn = 1.f; }      // image right border

        const float4 t = t_cur;
        const float4 p = p_cur;
        {
            const float wmx = fmaxf(fmaxf(Lmx, mx.x), mx.y);
            const float wmn = fminf(fminf(Lmn, mn.x), mn.y);
            const float w = (wmx > wmn) ? BWGT : 1.0f;
            const float x = (t.x != 0.0f) ? p.x : (1.0f - p.x);
            sum = fmaf(w, -__logf(x), sum);
        }
        {
            const float wmx = fmaxf(fmaxf(mx.x, mx.y), mx.z);
            const float wmn = fminf(fminf(mn.x, mn.y), mn.z);
            const float w = (wmx > wmn) ? BWGT : 1.0f;
            const float x = (t.y != 0.0f) ? p.y : (1.0f - p.y);
            sum = fmaf(w, -__logf(x), sum);
        }
        {
            const float wmx = fmaxf(fmaxf(mx.y, mx.z), mx.w);
            const float wmn = fminf(fminf(mn.y, mn.z), mn.w);
            const float w = (wmx > wmn) ? BWGT : 1.0f;
            const float x = (t.z != 0.0f) ? p.z : (1.0f - p.z);
            sum = fmaf(w, -__logf(x), sum);
        }
        {
            const float wmx = fmaxf(fmaxf(mx.z, mx.w), Rmx);
            const float wmn = fminf(fminf(mn.z, mn.w), Rmn);
            const float w = (wmx > wmn) ? BWGT : 1.0f;
            const float x = (t.w != 0.0f) ? p.w : (1.0f - p.w);
            sum = fmaf(w, -__logf(x), sum);
        }

        // ---- rotate the rolling window ----
        t_prev = t_cur;  t_cur = t_next;  t_next = t_nn;
        nb_prev = nb_cur; nb_cur = nb_next; nb_next = nb_nn;
        p_cur = p_nn;
    }

    // wave(64) shuffle reduce -> 4-wave LDS reduce -> one partial per block
    #pragma unroll
    for (int off = 32; off > 0; off >>= 1) sum += __shfl_down(sum, off);
    __shared__ float smem[4];
    if ((tid & 63) == 0) smem[tid >> 6] = sum;
    __syncthreads();
    if (tid == 0) partial[blockIdx.x] = (smem[0] + smem[1]) + (smem[2] + smem[3]);
}

__global__ __launch_bounds__(256) void bam_bce_reduce(
    const float* __restrict__ partial, float* __restrict__ out)
{
    const int tid = threadIdx.x;
    float s = 0.0f;
    for (int i = tid; i < GRID1; i += 256) s += partial[i];
    #pragma unroll
    for (int off = 32; off > 0; off >>= 1) s += __shfl_down(s, off);
    __shared__ float smem[4];
    if ((tid & 63) == 0) smem[tid >> 6] = s;
    __syncthreads();
    if (tid == 0) {
        const float invN = 1.0f / (float)((long long)Bn * Hn * Wn);  // 1/2^25, exact
        out[0] = ((smem[0] + smem[1]) + (smem[2] + smem[3])) * invN;
    }
}

extern "C" void kernel_launch(void* const* d_in, const int* in_sizes, int n_in,
                              void* d_out, int out_size, void* d_ws, size_t ws_size,
                              hipStream_t stream)
{
    const float* pred = (const float*)d_in[0];
    const float* tgt  = (const float*)d_in[1];
    float* partial = (float*)d_ws;            // 2048 floats = 8 KB, fully
                                              // overwritten each call (poison-safe)
    bam_bce_rows<<<GRID1, 256, 0, stream>>>(pred, tgt, partial);
    bam_bce_reduce<<<1, 256, 0, stream>>>(partial, (float*)d_out);
}

// Round 3
// 279.937 us; speedup vs baseline: 2.0000x; 1.0849x over previous
//
#include <hip/hip_runtime.h>
#include <math.h>

namespace {
constexpr int Bn = 32, Hn = 1024, Wn = 1024;
constexpr int STRIP = 8;                      // rows per block (divides Hn)
constexpr int GRID1 = Bn * Hn / STRIP;        // 4096 blocks -> 16 KB partials
constexpr float BWGT = 3.0f;
}

__device__ inline float4 vmax4(float4 a, float4 b) {
    return make_float4(fmaxf(a.x,b.x), fmaxf(a.y,b.y), fmaxf(a.z,b.z), fmaxf(a.w,b.w));
}
__device__ inline float4 vmin4(float4 a, float4 b) {
    return make_float4(fminf(a.x,b.x), fminf(a.y,b.y), fminf(a.z,b.z), fminf(a.w,b.w));
}

// R0's load-all-into-arrays structure (proven 80-VGPR regime) with the LDS
// edge exchange + __syncthreads REMOVED. The barrier forced a vmcnt(0) drain:
// all 28 loads had to land before any compute. Now halo columns for lanes
// 0/63 are read directly from global (exec-masked 4B loads; L1/L2-hit on the
// neighbor wave's lines — R2 measured FETCH 139 vs 147 MB, absmax 0.0), and
// the issue order is interleaved (target row r, halo r, pred r-1) so row-i
// compute depends only on the first ~3i+7 loads. The compiler's vmcnt-counted
// waits then overlap row-0 compute with the ~21 still-in-flight loads,
// per-wave, no block convoy.
// R1/R2 lessons encoded here: no __launch_bounds__ waves arg (R1: budget
// 256/8=32 VGPR -> 697 MB spill traffic); no rolling-window rotation chain
// (R2: unroll+hoist bloated to 148 VGPR -> occupancy 11%).
__global__ __launch_bounds__(256) void bam_bce_rows(
    const float* __restrict__ pred, const float* __restrict__ tgt,
    float* __restrict__ partial)
{
    const int tid  = threadIdx.x;
    const int lane = tid & 63;
    const int x0   = tid << 2;
    const int rowBase = blockIdx.x * STRIP;   // strips never cross images
    const int y0 = rowBase & (Hn - 1);
    const bool vtop = (y0 != 0);              // row y0-1 exists (block-uniform)
    const bool vbot = (y0 != Hn - STRIP);     // row y0+STRIP exists
    const float* tb = tgt  + (size_t)rowBase * Wn;
    const float* pb = pred + (size_t)rowBase * Wn;

    // halo-column loaders: lane 0 reads x0-1 (left neighbor's .w), lane 63
    // reads x0+4 (right neighbor's .x); image-border lanes load nothing.
    const bool isL = (lane == 0)  && (tid != 0);
    const bool isR = (lane == 63) && (tid != 255);
    const bool isEdge = isL || isR;
    const int  nbx = isL ? (x0 - 1) : (x0 + 4);   // only dereferenced if isEdge

    const float4 z4 = make_float4(0.f, 0.f, 0.f, 0.f);

    // ---- issue all loads, interleaved by row so waits are vmcnt-counted ----
    float4 tv[STRIP + 2];                     // target rows y0-1 .. y0+STRIP
    float  nb[STRIP + 2];                     // this lane's halo column (raw)
    float4 pv[STRIP];                         // pred rows y0 .. y0+STRIP-1
    tv[0] = z4; nb[0] = 0.f;
    if (vtop) {
        tv[0] = *reinterpret_cast<const float4*>(tb - Wn + x0);
        if (isEdge) nb[0] = tb[nbx - Wn];
    }
    #pragma unroll
    for (int r = 1; r <= STRIP; ++r) {
        tv[r] = *reinterpret_cast<const float4*>(tb + (r - 1) * Wn + x0);
        nb[r] = 0.f;
        if (isEdge) nb[r] = tb[(r - 1) * Wn + nbx];
        pv[r - 1] = *reinterpret_cast<const float4*>(pb + (r - 1) * Wn + x0);
    }
    tv[STRIP + 1] = z4; nb[STRIP + 1] = 0.f;
    if (vbot) {
        tv[STRIP + 1] = *reinterpret_cast<const float4*>(tb + STRIP * Wn + x0);
        if (isEdge) nb[STRIP + 1] = tb[STRIP * Wn + nbx];
    }

    float sum = 0.0f;
    #pragma unroll
    for (int i = 0; i < STRIP; ++i) {
        const bool useTop = (i > 0) || vtop;           // row r=i valid
        const bool useBot = (i < STRIP - 1) || vbot;   // row r=i+2 valid

        // vertical (3-row) max/min for own 4 columns + this lane's halo column
        float4 mx = tv[i + 1], mn = tv[i + 1];
        float  em = nb[i + 1], en = nb[i + 1];
        if (useTop) {
            mx = vmax4(mx, tv[i]); mn = vmin4(mn, tv[i]);
            em = fmaxf(em, nb[i]); en = fminf(en, nb[i]);
        }
        if (useBot) {
            mx = vmax4(mx, tv[i + 2]); mn = vmin4(mn, tv[i + 2]);
            em = fmaxf(em, nb[i + 2]); en = fminf(en, nb[i + 2]);
        }

        // horizontal neighbors: in-wave shuffle, patched at wave/image edges
        float Lmx = __shfl_up(mx.w, 1),   Lmn = __shfl_up(mn.w, 1);
        float Rmx = __shfl_down(mx.x, 1), Rmn = __shfl_down(mn.x, 1);
        if (lane == 0)  { Lmx = em; Lmn = en; }
        if (lane == 63) { Rmx = em; Rmn = en; }
        if (tid == 0)   { Lmx = 0.f; Lmn = 1.f; }      // image left border
        if (tid == 255) { Rmx = 0.f; Rmn = 1.f; }      // image right border

        const float4 t = tv[i + 1];
        const float4 p = pv[i];
        {
            const float wmx = fmaxf(fmaxf(Lmx, mx.x), mx.y);
            const float wmn = fminf(fminf(Lmn, mn.x), mn.y);
            const float w = (wmx > wmn) ? BWGT : 1.0f;
            const float x = (t.x != 0.0f) ? p.x : (1.0f - p.x);
            sum = fmaf(w, -__logf(x), sum);
        }
        {
            const float wmx = fmaxf(fmaxf(mx.x, mx.y), mx.z);
            const float wmn = fminf(fminf(mn.x, mn.y), mn.z);
            const float w = (wmx > wmn) ? BWGT : 1.0f;
            const float x = (t.y != 0.0f) ? p.y : (1.0f - p.y);
            sum = fmaf(w, -__logf(x), sum);
        }
        {
            const float wmx = fmaxf(fmaxf(mx.y, mx.z), mx.w);
            const float wmn = fminf(fminf(mn.y, mn.z), mn.w);
            const float w = (wmx > wmn) ? BWGT : 1.0f;
            const float x = (t.z != 0.0f) ? p.z : (1.0f - p.z);
            sum = fmaf(w, -__logf(x), sum);
        }
        {
            const float wmx = fmaxf(fmaxf(mx.z, mx.w), Rmx);
            const float wmn = fminf(fminf(mn.z, mn.w), Rmn);
            const float w = (wmx > wmn) ? BWGT : 1.0f;
            const float x = (t.w != 0.0f) ? p.w : (1.0f - p.w);
            sum = fmaf(w, -__logf(x), sum);
        }
    }

    // wave(64) shuffle reduce -> 4-wave LDS reduce -> one partial per block
    #pragma unroll
    for (int off = 32; off > 0; off >>= 1) sum += __shfl_down(sum, off);
    __shared__ float smem[4];
    if ((tid & 63) == 0) smem[tid >> 6] = sum;
    __syncthreads();
    if (tid == 0) partial[blockIdx.x] = (smem[0] + smem[1]) + (smem[2] + smem[3]);
}

__global__ __launch_bounds__(256) void bam_bce_reduce(
    const float* __restrict__ partial, float* __restrict__ out)
{
    const int tid = threadIdx.x;
    float s = 0.0f;
    for (int i = tid; i < GRID1; i += 256) s += partial[i];
    #pragma unroll
    for (int off = 32; off > 0; off >>= 1) s += __shfl_down(s, off);
    __shared__ float smem[4];
    if ((tid & 63) == 0) smem[tid >> 6] = s;
    __syncthreads();
    if (tid == 0) {
        const float invN = 1.0f / (float)((long long)Bn * Hn * Wn);  // 1/2^25, exact
        out[0] = ((smem[0] + smem[1]) + (smem[2] + smem[3])) * invN;
    }
}

extern "C" void kernel_launch(void* const* d_in, const int* in_sizes, int n_in,
                              void* d_out, int out_size, void* d_ws, size_t ws_size,
                              hipStream_t stream)
{
    const float* pred = (const float*)d_in[0];
    const float* tgt  = (const float*)d_in[1];
    float* partial = (float*)d_ws;            // 4096 floats = 16 KB, fully
                                              // overwritten each call (poison-safe)
    bam_bce_rows<<<GRID1, 256, 0, stream>>>(pred, tgt, partial);
    bam_bce_reduce<<<1, 256, 0, stream>>>(partial, (float*)d_out);
}